// Round 10
// baseline (763.124 us; speedup 1.0000x reference)
//
#include <hip/hip_runtime.h>
#include <cstdint>
#include <cstddef>

#define B_   64
#define T_   256
#define DIN_ 128
#define H_   256
#define G3_  768   // 3*H

typedef _Float16 f16x8 __attribute__((ext_vector_type(8)));
typedef float    f32x4 __attribute__((ext_vector_type(4)));

#define MFMA(a, b, c) __builtin_amdgcn_mfma_f32_16x16x32_f16((a), (b), (c), 0, 0, 0)

// ---------- helpers ----------
__device__ __forceinline__ unsigned short f2h(float f) {
  _Float16 h = (_Float16)f;              // v_cvt_f16_f32 (RNE)
  return __builtin_bit_cast(unsigned short, h);
}

// ---------- prep ----------
// Wreg layout for 16-wave MFMA gru (1024 threads/block):
//   frag index fi = g*8 + kf   (g=gate 0..2, kf=K-frag 0..7)
//   thread tid: wave w=tid>>6, lane l=tid&63; output u = w*16 + (l&15)
//   B-frag dword d holds fp16 pair (k, k+1), k = kf*32 + (l>>4)*8 + 2d
//   Wreg dword m = (fi*1024 + tid)*4 + d -> coalesced uint4 loads W4[fi*1024+tid]
__global__ __launch_bounds__(256) void prep_kernel(
    const float* __restrict__ W_ih, const float* __restrict__ W_hh,
    const float* __restrict__ W_mz, const float* __restrict__ W_mx,
    const float* __restrict__ W_pz, const float* __restrict__ W_cx,
    float* __restrict__ WT_ih, float* __restrict__ WheadT,
    unsigned* __restrict__ Wreg) {
  int i = blockIdx.x * 256 + threadIdx.x;
  if (i < 98304) {                       // WT_ih[k*768+g] = W_ih[g*128+k]
    int k = i / 768, g = i % 768;
    WT_ih[i] = W_ih[g * 128 + k];
  } else if (i < 98304 + 24576) {        // WheadT[c*256+k]
    int j = i - 98304;
    int c = j >> 8, k = j & 255;
    float v;
    if (c < 8)       v = W_mz[c * 256 + k];
    else if (c < 16) v = W_mx[(c - 8) * 256 + k];
    else if (c < 32) v = W_pz[(c - 16) * 256 + k];
    else             v = W_cx[(c - 32) * 256 + k];
    WheadT[j] = v;
  } else {                               // W_hh fp16 B-frag repack (16-wave layout)
    int m = i - 122880;                  // 0..98303
    int d = m & 3, n = m >> 2;           // d = frag dword
    int tid = n & 1023, fi = n >> 10;    // fi in [0,24)
    int g  = fi >> 3, kf = fi & 7;
    int wv = tid >> 6, l = tid & 63;
    int u = wv * 16 + (l & 15);
    int k = kf * 32 + ((l >> 4) << 3) + 2 * d;
    int row = g * 256 + u;
    unsigned short lo = f2h(W_hh[row * 256 + k]);
    unsigned short hi = f2h(W_hh[row * 256 + k + 1]);
    Wreg[m] = ((unsigned)hi << 16) | (unsigned)lo;
  }
}

// ---------- x_proj = y @ W_ih^T + b_ih (+ b_hh folded for r,z gates) ----------
// 512 blocks: blockIdx>>1 selects 64-row stripe, blockIdx&1 selects 3 of 6 col-tiles.
__global__ __launch_bounds__(256) void xproj_kernel(
    const float* __restrict__ y, const float* __restrict__ WT_ih,
    const float* __restrict__ b_ih, const float* __restrict__ b_hh,
    float* __restrict__ xp) {
  __shared__ float ylds[64][132];
  int tid = threadIdx.x;
  int row0 = (blockIdx.x >> 1) * 64;
  int c0 = (blockIdx.x & 1) * 3;
  const float4* y4 = (const float4*)(y + (size_t)row0 * DIN_);
#pragma unroll
  for (int i = 0; i < 8; ++i) {
    int idx = i * 256 + tid;             // 2048 float4 = 64x128
    float4 v = y4[idx];
    int r = idx >> 5, c4 = (idx & 31) * 4;
    ylds[r][c4 + 0] = v.x; ylds[r][c4 + 1] = v.y;
    ylds[r][c4 + 2] = v.z; ylds[r][c4 + 3] = v.w;
  }
  __syncthreads();
  int tx = tid & 15, ty = tid >> 4;      // thread: 4 rows x 8 cols
  for (int c = c0; c < c0 + 3; ++c) {
    int col0 = c * 128 + tx * 8;
    float acc[4][8];
#pragma unroll
    for (int a = 0; a < 4; ++a)
#pragma unroll
      for (int b = 0; b < 8; ++b) acc[a][b] = 0.f;
#pragma unroll 4
    for (int k = 0; k < 128; ++k) {
      float4 w0 = *(const float4*)&WT_ih[k * 768 + col0];
      float4 w1 = *(const float4*)&WT_ih[k * 768 + col0 + 4];
      float a0 = ylds[ty * 4 + 0][k], a1 = ylds[ty * 4 + 1][k];
      float a2 = ylds[ty * 4 + 2][k], a3 = ylds[ty * 4 + 3][k];
      acc[0][0] += a0 * w0.x; acc[0][1] += a0 * w0.y; acc[0][2] += a0 * w0.z; acc[0][3] += a0 * w0.w;
      acc[0][4] += a0 * w1.x; acc[0][5] += a0 * w1.y; acc[0][6] += a0 * w1.z; acc[0][7] += a0 * w1.w;
      acc[1][0] += a1 * w0.x; acc[1][1] += a1 * w0.y; acc[1][2] += a1 * w0.z; acc[1][3] += a1 * w0.w;
      acc[1][4] += a1 * w1.x; acc[1][5] += a1 * w1.y; acc[1][6] += a1 * w1.z; acc[1][7] += a1 * w1.w;
      acc[2][0] += a2 * w0.x; acc[2][1] += a2 * w0.y; acc[2][2] += a2 * w0.z; acc[2][3] += a2 * w0.w;
      acc[2][4] += a2 * w1.x; acc[2][5] += a2 * w1.y; acc[2][6] += a2 * w1.z; acc[2][7] += a2 * w1.w;
      acc[3][0] += a3 * w0.x; acc[3][1] += a3 * w0.y; acc[3][2] += a3 * w0.z; acc[3][3] += a3 * w0.w;
      acc[3][4] += a3 * w1.x; acc[3][5] += a3 * w1.y; acc[3][6] += a3 * w1.z; acc[3][7] += a3 * w1.w;
    }
    float4 b0 = *(const float4*)&b_ih[col0];
    float4 b1 = *(const float4*)&b_ih[col0 + 4];
    if (c < 4) {                         // fold b_hh into r,z gate columns (<512)
      float4 h0 = *(const float4*)&b_hh[col0];
      float4 h1 = *(const float4*)&b_hh[col0 + 4];
      b0.x += h0.x; b0.y += h0.y; b0.z += h0.z; b0.w += h0.w;
      b1.x += h1.x; b1.y += h1.y; b1.z += h1.z; b1.w += h1.w;
    }
#pragma unroll
    for (int a = 0; a < 4; ++a) {
      int row = row0 + ty * 4 + a;
      float4 o0, o1;
      o0.x = acc[a][0] + b0.x; o0.y = acc[a][1] + b0.y; o0.z = acc[a][2] + b0.z; o0.w = acc[a][3] + b0.w;
      o1.x = acc[a][4] + b1.x; o1.y = acc[a][5] + b1.y; o1.z = acc[a][6] + b1.z; o1.w = acc[a][7] + b1.w;
      *(float4*)&xp[(size_t)row * G3_ + col0] = o0;
      *(float4*)&xp[(size_t)row * G3_ + col0 + 4] = o1;
    }
  }
}

// ---------- GRU recurrence via MFMA: blocks 0-63; blocks 64-159 zero chol upper --
// 16 waves x 64 lanes. Wave w owns outputs [16w, 16w+16) for all 3 gates.
// Gate-blocked MFMA order with SPLIT accumulators (2x4 chains per gate):
// R and Z complete ~1/3 of the step early, so their sigmoid chains issue
// under the N-gate MFMAs; only the tanh tail is exposed at the barrier.
// Lane l computes output u = 16w + (l&15); 16-lane groups are replicas,
// group 0 writes. One barrier per step, double-buffered fp16 h in LDS.
__global__ __launch_bounds__(1024) void gru_kernel(
    const float* __restrict__ xp, const unsigned* __restrict__ Wreg,
    const float* __restrict__ b_hh, float* enc, float4* __restrict__ cholU) {
  int tid = threadIdx.x;
  int b = blockIdx.x;
  if (b >= 64) {                         // ---- tail blocks: zero chol upper half
    float4 zz = {0.f, 0.f, 0.f, 0.f};    //      (concurrent with the recurrence)
    int idx = (b - 64) * 1024 + tid;     // 96*1024 = 98304 threads
    for (; idx < 4194304; idx += 98304) cholU[idx] = zz;
    return;
  }
  int w = tid >> 6;
  int l = tid & 63;
  int g16 = l >> 4;                      // replica / K-chunk group
  int u = w * 16 + (l & 15);
  __shared__ alignas(16) unsigned short h16[2][256];   // double-buffered h

  f16x8 wfR[8], wfZ[8], wfN[8];          // W_hh B-frags (AGPR-resident, ok)
  const uint4* W4 = (const uint4*)Wreg;
#pragma unroll
  for (int kf = 0; kf < 8; ++kf) {
    wfR[kf] = __builtin_bit_cast(f16x8, W4[(0 * 8 + kf) * 1024 + tid]);
    wfZ[kf] = __builtin_bit_cast(f16x8, W4[(1 * 8 + kf) * 1024 + tid]);
    wfN[kf] = __builtin_bit_cast(f16x8, W4[(2 * 8 + kf) * 1024 + tid]);
  }
  if (tid < 32) {                        // h0 = 0 (buffer 0 = first 32 uint4)
    uint4 z = {0u, 0u, 0u, 0u};
    ((uint4*)h16)[tid] = z;
  }
  const float* xpb = xp + (size_t)b * (T_ * G3_);
  float* encb = enc + (size_t)b * (T_ * H_);
  float bhn = b_hh[512 + u];
  float hold = 0.f;
  const f32x4 z4 = {0.f, 0.f, 0.f, 0.f};
  __syncthreads();
  const uint4* h4 = (const uint4*)h16;
  for (int t = 0; t < T_; ++t) {
    asm volatile("" ::: "memory");       // keep load placement per-step
    const float* xq = xpb + (size_t)t * G3_;
    // issue xp loads at step top; latency hides under the 24-MFMA body
    float xr = xq[u], xz = xq[256 + u], xn = xq[512 + u];
    int cur = t & 1;
    const uint4* hb = h4 + cur * 32 + g16;
    f16x8 h0 = __builtin_bit_cast(f16x8, hb[0]);
    f16x8 h1 = __builtin_bit_cast(f16x8, hb[4]);
    f16x8 h2 = __builtin_bit_cast(f16x8, hb[8]);
    f16x8 h3 = __builtin_bit_cast(f16x8, hb[12]);
    // first-half chains (kf 0..3)
    f32x4 aR0 = MFMA(h0, wfR[0], z4); aR0 = MFMA(h1, wfR[1], aR0);
    aR0 = MFMA(h2, wfR[2], aR0);      aR0 = MFMA(h3, wfR[3], aR0);
    f32x4 aZ0 = MFMA(h0, wfZ[0], z4); aZ0 = MFMA(h1, wfZ[1], aZ0);
    aZ0 = MFMA(h2, wfZ[2], aZ0);      aZ0 = MFMA(h3, wfZ[3], aZ0);
    f32x4 aN0 = MFMA(h0, wfN[0], z4); aN0 = MFMA(h1, wfN[1], aN0);
    aN0 = MFMA(h2, wfN[2], aN0);      aN0 = MFMA(h3, wfN[3], aN0);
    // second-half chains (kf 4..7)
    f16x8 h4_ = __builtin_bit_cast(f16x8, hb[16]);
    f16x8 h5  = __builtin_bit_cast(f16x8, hb[20]);
    f16x8 h6  = __builtin_bit_cast(f16x8, hb[24]);
    f16x8 h7  = __builtin_bit_cast(f16x8, hb[28]);
    f32x4 aR1 = MFMA(h4_, wfR[4], z4); aR1 = MFMA(h5, wfR[5], aR1);
    aR1 = MFMA(h6, wfR[6], aR1);       aR1 = MFMA(h7, wfR[7], aR1);
    f32x4 aZ1 = MFMA(h4_, wfZ[4], z4); aZ1 = MFMA(h5, wfZ[5], aZ1);
    aZ1 = MFMA(h6, wfZ[6], aZ1);       aZ1 = MFMA(h7, wfZ[7], aZ1);
    // r,z pointwise issues here, overlapping the N second-half MFMAs
    float pr = (aR0[0] + aR1[0]) + xr;
    float pz = (aZ0[0] + aZ1[0]) + xz;
    float r_ = 1.f / (1.f + __expf(-pr));
    float q_ = 1.f / (1.f + __expf(-pz));
    float zh = q_ * hold, om = 1.f - q_;
    f32x4 aN1 = MFMA(h4_, wfN[4], z4); aN1 = MFMA(h5, wfN[5], aN1);
    aN1 = MFMA(h6, wfN[6], aN1);       aN1 = MFMA(h7, wfN[7], aN1);
    float pn = (aN0[0] + aN1[0]) + bhn;
    float a = xn + r_ * pn;
    a = fminf(15.f, fmaxf(-15.f, a));
    float e = __expf(2.f * a);
    float n = (e - 1.f) / (e + 1.f);     // tanh
    float hn = om * n + zh;
    hold = hn;                           // exact fp32 state (replicated lanes)
    if (g16 == 0) {                      // one writer replica per wave
      encb[t * H_ + u] = hn;
      h16[cur ^ 1][u] = f2h(hn);
    }
    __syncthreads();                     // new h visible to all waves
  }
}

// ---------- heads: 512 blocks, fused lower-chol fill + in-block anchor ---------
// Each block owns 32 (b,t) rows. Matvec outputs: mean_z/mean_x/cov_x direct;
// pz diag/off: d<4 staged in LDS then the block writes its rows' FULL lower
// chol rows (zero+diag+off, coalesced float4); d=4..7 scattered directly into
// the upper half (zeroed by gru tail blocks; stream order guarantees done).
// Lower-half writes are safe: d=0..2 rows overlap only dead xp scratch; d=3
// rows overlap exactly this block's own enc rows (already staged in LDS).
// Blocks owning t=0 also compute anchor[b] from the LDS copy.
__global__ __launch_bounds__(384) void heads_kernel(
    const float* __restrict__ enc, const float* __restrict__ WheadT,
    const float* __restrict__ b_mz, const float* __restrict__ b_mx,
    const float* __restrict__ b_pz, const float* __restrict__ b_cx,
    float* __restrict__ out_meanz, float* __restrict__ out_meanx,
    float* __restrict__ out_covx, float* __restrict__ chol,
    float* __restrict__ anchor, const float* __restrict__ W_mx) {
  __shared__ float el[32 * 256];         // 32 KB
  __shared__ float dsd[32][4], dso[32][4];
  __shared__ float redA[4], redB[4];
  int tid = threadIdx.x;
  int row0 = blockIdx.x * 32;
  const float4* e4 = (const float4*)(enc + (size_t)row0 * 256);
  float4* el4 = (float4*)el;
#pragma unroll
  for (int i = 0; i < 6; ++i) {
    int idx = i * 384 + tid;             // 2048 float4 = 32x64
    if (idx < 2048) el4[idx] = e4[idx];
  }
  __syncthreads();
  int rg = tid / 96, c = tid - rg * 96;  // rg in [0,4), c in [0,96)
  const float4* Wc = (const float4*)(WheadT + c * 256);
  float acc[8];
#pragma unroll
  for (int r = 0; r < 8; ++r) acc[r] = 0.f;
  for (int k4 = 0; k4 < 64; ++k4) {
    float4 w4 = Wc[k4];
#pragma unroll
    for (int r = 0; r < 8; ++r) {
      float4 ev = el4[(rg * 8 + r) * 64 + k4];
      acc[r] += w4.x * ev.x; acc[r] += w4.y * ev.y;
      acc[r] += w4.z * ev.z; acc[r] += w4.w * ev.w;
    }
  }
#pragma unroll
  for (int r = 0; r < 8; ++r) {
    int lr = rg * 8 + r;
    int row = row0 + lr;
    float a_ = acc[r];
    if (c < 8) {
      out_meanz[(size_t)row * 8 + c] = a_ + b_mz[c];
    } else if (c < 16) {
      int d = c - 8;
      out_meanx[(size_t)row * 8 + d] = a_ + b_mx[d];   // anchor applied later
    } else if (c < 32) {
      int d = c - 16;
      float v = a_ + b_pz[d];
      if (d < 8)                          // diag: softplus (stable)
        v = (v > 0.f) ? (v + log1pf(__expf(-v))) : log1pf(__expf(v));
      int bb = row >> 8, tt = row & 255;
      if (d < 4) {
        dsd[lr][d] = v;                                 // lower diag (LDS)
      } else if (d < 8) {                               // upper diag: direct
        chol[(((size_t)d * 64 + bb) * 256 + tt) * 256 + tt] = v;
      } else if (d < 12) {
        dso[lr][d - 8] = v;                             // lower off (LDS)
      } else {                                          // upper off: direct
        int dd = d - 8;
        if (tt < 255)
          chol[(((size_t)dd * 64 + bb) * 256 + tt) * 256 + tt + 1] = v;
      }
    } else {
      int d = c - 32;
      out_covx[(size_t)row * 64 + d] = a_ + b_cx[d];
    }
  }
  // in-block anchor for blocks owning t=0 (reads the LDS enc copy, race-free)
  bool anch = (row0 & 255) == 0;
  if (anch && tid < 256) {
    float e0 = el[tid];
    float va0 = e0 * W_mx[tid];
    float va1 = e0 * W_mx[256 + tid];
#pragma unroll
    for (int off = 32; off >= 1; off >>= 1) {
      va0 += __shfl_down(va0, off, 64);
      va1 += __shfl_down(va1, off, 64);
    }
    if ((tid & 63) == 0) { redA[tid >> 6] = va0; redB[tid >> 6] = va1; }
  }
  __syncthreads();                       // dsd/dso/red visible
  if (anch && tid == 0) {
    int b = row0 >> 8;
    anchor[b * 2 + 0] = b_mx[0] + ((redA[0] + redA[1]) + (redA[2] + redA[3]));
    anchor[b * 2 + 1] = b_mx[1] + ((redB[0] + redB[1]) + (redB[2] + redB[3]));
  }
  // cooperative lower-half row fill: 4 d x 32 rows x 64 float4 = 8192
  float4* chol4 = (float4*)chol;
  for (int idx = tid; idx < 8192; idx += 384) {
    int j = idx & 63, lr = (idx >> 6) & 31, d = idx >> 11;
    int grow = row0 + lr;
    int bb = grow >> 8, tt = grow & 255;
    int jd = tt >> 2, jo = (tt + 1) >> 2;            // jo==64 at tt==255: excluded
    float vd = (j == jd) ? dsd[lr][d] : 0.f;
    float vo = (j == jo) ? dso[lr][d] : 0.f;
    int te = tt & 3, oe = (tt + 1) & 3;
    float4 v;
    v.x = (te == 0 ? vd : 0.f) + (oe == 0 ? vo : 0.f);
    v.y = (te == 1 ? vd : 0.f) + (oe == 1 ? vo : 0.f);
    v.z = (te == 2 ? vd : 0.f) + (oe == 2 ? vo : 0.f);
    v.w = (te == 3 ? vd : 0.f) + (oe == 3 ? vo : 0.f);
    chol4[(((size_t)d * 64 + bb) * 256 + tt) * 64 + j] = v;
  }
}

// ---------- final: mean_x anchor fix only (32768 elements) ----------
__global__ __launch_bounds__(256) void chol_fin(
    const float* __restrict__ anchor, float* __restrict__ mean_x) {
  int j = blockIdx.x * 256 + threadIdx.x;   // 128 blocks x 256 = 32768
  int row = j >> 1, d = j & 1;
  mean_x[(size_t)row * 8 + d] -= anchor[(row >> 8) * 2 + d];
}

extern "C" void kernel_launch(void* const* d_in, const int* in_sizes, int n_in,
                              void* d_out, int out_size, void* d_ws, size_t ws_size,
                              hipStream_t stream) {
  const float* y    = (const float*)d_in[0];
  const float* W_ih = (const float*)d_in[1];
  const float* W_hh = (const float*)d_in[2];
  const float* b_ih = (const float*)d_in[3];
  const float* b_hh = (const float*)d_in[4];
  const float* W_mz = (const float*)d_in[5];
  const float* b_mz = (const float*)d_in[6];
  const float* W_mx = (const float*)d_in[7];
  const float* b_mx = (const float*)d_in[8];
  const float* W_pz = (const float*)d_in[9];
  const float* b_pz = (const float*)d_in[10];
  const float* W_cx = (const float*)d_in[11];
  const float* b_cx = (const float*)d_in[12];

  float* out    = (float*)d_out;
  float* mean_z = out;                    // [64,256,8]
  float* chol   = out + 131072;           // [8,64,256,256]
  float* mean_x = out + 33685504;         // [16384,8]
  float* cov_x  = out + 33816576;         // [16384,8,8]

  float* ws      = (float*)d_ws;
  float* WT_ih   = ws;                    // 98304
  float* WheadT  = ws + 98304;            // 24576
  unsigned* Wreg = (unsigned*)(ws + 122880); // 98304
  float* anchor  = ws + 221184;           // 128

  // large scratch inside the chol LOWER half (rewritten by heads at end);
  // upper half [16777216,33554432) is zeroed by gru tail blocks (overlapped).
  float* xp  = chol;                      // 12582912 floats
  float* enc = chol + 12582912;           // 4194304 floats (ends at 16777216)

  prep_kernel<<<864, 256, 0, stream>>>(W_ih, W_hh, W_mz, W_mx, W_pz, W_cx,
                                       WT_ih, WheadT, Wreg);
  xproj_kernel<<<512, 256, 0, stream>>>(y, WT_ih, b_ih, b_hh, xp);
  gru_kernel<<<160, 1024, 0, stream>>>(xp, Wreg, b_hh, enc,
                                       ((float4*)chol) + 4194304);
  heads_kernel<<<512, 384, 0, stream>>>(enc, WheadT, b_mz, b_mx, b_pz, b_cx,
                                        mean_z, mean_x, cov_x, chol,
                                        anchor, W_mx);
  chol_fin<<<128, 256, 0, stream>>>(anchor, mean_x);
}

// Round 11
// 536.922 us; speedup vs baseline: 1.4213x; 1.4213x over previous
//
#include <hip/hip_runtime.h>
#include <cstdint>
#include <cstddef>

#define B_   64
#define T_   256
#define DIN_ 128
#define H_   256
#define G3_  768   // 3*H

typedef _Float16 f16x8 __attribute__((ext_vector_type(8)));
typedef float    f32x4 __attribute__((ext_vector_type(4)));

#define MFMA(a, b, c) __builtin_amdgcn_mfma_f32_16x16x32_f16((a), (b), (c), 0, 0, 0)

// ---------- helpers ----------
__device__ __forceinline__ unsigned short f2h(float f) {
  _Float16 h = (_Float16)f;              // v_cvt_f16_f32 (RNE)
  return __builtin_bit_cast(unsigned short, h);
}

// ---------- prep ----------
// Wreg layout for 16-wave MFMA gru (1024 threads/block):
//   frag index fi = g*8 + kf   (g=gate 0..2, kf=K-frag 0..7)
//   thread tid: wave w=tid>>6, lane l=tid&63; output u = w*16 + (l&15)
//   B-frag dword d holds fp16 pair (k, k+1), k = kf*32 + (l>>4)*8 + 2d
//   Wreg dword m = (fi*1024 + tid)*4 + d -> coalesced uint4 loads W4[fi*1024+tid]
__global__ __launch_bounds__(256) void prep_kernel(
    const float* __restrict__ W_ih, const float* __restrict__ W_hh,
    const float* __restrict__ W_mz, const float* __restrict__ W_mx,
    const float* __restrict__ W_pz, const float* __restrict__ W_cx,
    float* __restrict__ WT_ih, float* __restrict__ WheadT,
    unsigned* __restrict__ Wreg) {
  int i = blockIdx.x * 256 + threadIdx.x;
  if (i < 98304) {                       // WT_ih[k*768+g] = W_ih[g*128+k]
    int k = i / 768, g = i % 768;
    WT_ih[i] = W_ih[g * 128 + k];
  } else if (i < 98304 + 24576) {        // WheadT[c*256+k]
    int j = i - 98304;
    int c = j >> 8, k = j & 255;
    float v;
    if (c < 8)       v = W_mz[c * 256 + k];
    else if (c < 16) v = W_mx[(c - 8) * 256 + k];
    else if (c < 32) v = W_pz[(c - 16) * 256 + k];
    else             v = W_cx[(c - 32) * 256 + k];
    WheadT[j] = v;
  } else {                               // W_hh fp16 B-frag repack (16-wave layout)
    int m = i - 122880;                  // 0..98303
    int d = m & 3, n = m >> 2;           // d = frag dword
    int tid = n & 1023, fi = n >> 10;    // fi in [0,24)
    int g  = fi >> 3, kf = fi & 7;
    int wv = tid >> 6, l = tid & 63;
    int u = wv * 16 + (l & 15);
    int k = kf * 32 + ((l >> 4) << 3) + 2 * d;
    int row = g * 256 + u;
    unsigned short lo = f2h(W_hh[row * 256 + k]);
    unsigned short hi = f2h(W_hh[row * 256 + k + 1]);
    Wreg[m] = ((unsigned)hi << 16) | (unsigned)lo;
  }
}

// ---------- x_proj = y @ W_ih^T + b_ih (+ b_hh folded for r,z gates) ----------
// 512 blocks: blockIdx>>1 selects 64-row stripe, blockIdx&1 selects 3 of 6 col-tiles.
__global__ __launch_bounds__(256) void xproj_kernel(
    const float* __restrict__ y, const float* __restrict__ WT_ih,
    const float* __restrict__ b_ih, const float* __restrict__ b_hh,
    float* __restrict__ xp) {
  __shared__ float ylds[64][132];
  int tid = threadIdx.x;
  int row0 = (blockIdx.x >> 1) * 64;
  int c0 = (blockIdx.x & 1) * 3;
  const float4* y4 = (const float4*)(y + (size_t)row0 * DIN_);
#pragma unroll
  for (int i = 0; i < 8; ++i) {
    int idx = i * 256 + tid;             // 2048 float4 = 64x128
    float4 v = y4[idx];
    int r = idx >> 5, c4 = (idx & 31) * 4;
    ylds[r][c4 + 0] = v.x; ylds[r][c4 + 1] = v.y;
    ylds[r][c4 + 2] = v.z; ylds[r][c4 + 3] = v.w;
  }
  __syncthreads();
  int tx = tid & 15, ty = tid >> 4;      // thread: 4 rows x 8 cols
  for (int c = c0; c < c0 + 3; ++c) {
    int col0 = c * 128 + tx * 8;
    float acc[4][8];
#pragma unroll
    for (int a = 0; a < 4; ++a)
#pragma unroll
      for (int b = 0; b < 8; ++b) acc[a][b] = 0.f;
#pragma unroll 4
    for (int k = 0; k < 128; ++k) {
      float4 w0 = *(const float4*)&WT_ih[k * 768 + col0];
      float4 w1 = *(const float4*)&WT_ih[k * 768 + col0 + 4];
      float a0 = ylds[ty * 4 + 0][k], a1 = ylds[ty * 4 + 1][k];
      float a2 = ylds[ty * 4 + 2][k], a3 = ylds[ty * 4 + 3][k];
      acc[0][0] += a0 * w0.x; acc[0][1] += a0 * w0.y; acc[0][2] += a0 * w0.z; acc[0][3] += a0 * w0.w;
      acc[0][4] += a0 * w1.x; acc[0][5] += a0 * w1.y; acc[0][6] += a0 * w1.z; acc[0][7] += a0 * w1.w;
      acc[1][0] += a1 * w0.x; acc[1][1] += a1 * w0.y; acc[1][2] += a1 * w0.z; acc[1][3] += a1 * w0.w;
      acc[1][4] += a1 * w1.x; acc[1][5] += a1 * w1.y; acc[1][6] += a1 * w1.z; acc[1][7] += a1 * w1.w;
      acc[2][0] += a2 * w0.x; acc[2][1] += a2 * w0.y; acc[2][2] += a2 * w0.z; acc[2][3] += a2 * w0.w;
      acc[2][4] += a2 * w1.x; acc[2][5] += a2 * w1.y; acc[2][6] += a2 * w1.z; acc[2][7] += a2 * w1.w;
      acc[3][0] += a3 * w0.x; acc[3][1] += a3 * w0.y; acc[3][2] += a3 * w0.z; acc[3][3] += a3 * w0.w;
      acc[3][4] += a3 * w1.x; acc[3][5] += a3 * w1.y; acc[3][6] += a3 * w1.z; acc[3][7] += a3 * w1.w;
    }
    float4 b0 = *(const float4*)&b_ih[col0];
    float4 b1 = *(const float4*)&b_ih[col0 + 4];
    if (c < 4) {                         // fold b_hh into r,z gate columns (<512)
      float4 h0 = *(const float4*)&b_hh[col0];
      float4 h1 = *(const float4*)&b_hh[col0 + 4];
      b0.x += h0.x; b0.y += h0.y; b0.z += h0.z; b0.w += h0.w;
      b1.x += h1.x; b1.y += h1.y; b1.z += h1.z; b1.w += h1.w;
    }
#pragma unroll
    for (int a = 0; a < 4; ++a) {
      int row = row0 + ty * 4 + a;
      float4 o0, o1;
      o0.x = acc[a][0] + b0.x; o0.y = acc[a][1] + b0.y; o0.z = acc[a][2] + b0.z; o0.w = acc[a][3] + b0.w;
      o1.x = acc[a][4] + b1.x; o1.y = acc[a][5] + b1.y; o1.z = acc[a][6] + b1.z; o1.w = acc[a][7] + b1.w;
      *(float4*)&xp[(size_t)row * G3_ + col0] = o0;
      *(float4*)&xp[(size_t)row * G3_ + col0 + 4] = o1;
    }
  }
}

// ---------- GRU recurrence via MFMA: blocks 0-63; blocks 64-159 zero chol upper --
// 16 waves x 64 lanes. Wave w owns outputs [16w, 16w+16) for all 3 gates.
// ROUND-7-VERIFIED inner loop: per kf load ONE h-frag, issue R/Z/N MFMAs
// interleaved (3 independent accumulator chains, minimal live VGPR state —
// critical under the 64-arch-VGPR allocation; round 10's blocked order with
// 8 live h-frags + 6 accumulators regressed 301->522 us).
// Lane l computes output u = 16w + (l&15); 16-lane groups are replicas,
// group 0 writes. One barrier per step, double-buffered fp16 h in LDS.
__global__ __launch_bounds__(1024) void gru_kernel(
    const float* __restrict__ xp, const unsigned* __restrict__ Wreg,
    const float* __restrict__ b_hh, float* enc, float4* __restrict__ cholU) {
  int tid = threadIdx.x;
  int b = blockIdx.x;
  if (b >= 64) {                         // ---- tail blocks: zero chol upper half
    float4 zz = {0.f, 0.f, 0.f, 0.f};    //      (concurrent with the recurrence)
    int idx = (b - 64) * 1024 + tid;     // 96*1024 = 98304 threads
    for (; idx < 4194304; idx += 98304) cholU[idx] = zz;
    return;
  }
  int w = tid >> 6;
  int l = tid & 63;
  int g16 = l >> 4;                      // replica / K-chunk group
  int u = w * 16 + (l & 15);
  __shared__ alignas(16) unsigned short h16[2][256];   // double-buffered h

  f16x8 wfR[8], wfZ[8], wfN[8];          // W_hh B-frags (AGPR-resident, ok)
  const uint4* W4 = (const uint4*)Wreg;
#pragma unroll
  for (int kf = 0; kf < 8; ++kf) {
    wfR[kf] = __builtin_bit_cast(f16x8, W4[(0 * 8 + kf) * 1024 + tid]);
    wfZ[kf] = __builtin_bit_cast(f16x8, W4[(1 * 8 + kf) * 1024 + tid]);
    wfN[kf] = __builtin_bit_cast(f16x8, W4[(2 * 8 + kf) * 1024 + tid]);
  }
  if (tid < 32) {                        // h0 = 0 (buffer 0 = first 32 uint4)
    uint4 z = {0u, 0u, 0u, 0u};
    ((uint4*)h16)[tid] = z;
  }
  const float* xpb = xp + (size_t)b * (T_ * G3_);
  float* encb = enc + (size_t)b * (T_ * H_);
  float bhn = b_hh[512 + u];
  float hold = 0.f;
  const f32x4 z4 = {0.f, 0.f, 0.f, 0.f};
  __syncthreads();
  const uint4* h4 = (const uint4*)h16;
  for (int t = 0; t < T_; ++t) {
    asm volatile("" ::: "memory");       // keep load placement per-step
    const float* xq = xpb + (size_t)t * G3_;
    // issue xp loads at step top; latency hides under the 24-MFMA body
    float xr = xq[u], xz = xq[256 + u], xn = xq[512 + u];
    int cur = t & 1;
    f32x4 aR, aZ, aN;
    {
      uint4 hq = h4[cur * 32 + g16];
      f16x8 hk = __builtin_bit_cast(f16x8, hq);
      aR = MFMA(hk, wfR[0], z4);
      aZ = MFMA(hk, wfZ[0], z4);
      aN = MFMA(hk, wfN[0], z4);
    }
#pragma unroll
    for (int kf = 1; kf < 8; ++kf) {
      uint4 hq = h4[cur * 32 + kf * 4 + g16];
      f16x8 hk = __builtin_bit_cast(f16x8, hq);
      aR = MFMA(hk, wfR[kf], aR);
      aZ = MFMA(hk, wfZ[kf], aZ);
      aN = MFMA(hk, wfN[kf], aN);
    }
    // r,z first so the sigmoid chain overlaps the tail of the N accumulate
    float pr = aR[0] + xr, pz = aZ[0] + xz;
    float r_ = 1.f / (1.f + __expf(-pr));
    float q_ = 1.f / (1.f + __expf(-pz));
    float zh = q_ * hold, om = 1.f - q_;
    float pn = aN[0] + bhn;
    float a = xn + r_ * pn;
    a = fminf(15.f, fmaxf(-15.f, a));
    float e = __expf(2.f * a);
    float n = (e - 1.f) / (e + 1.f);     // tanh
    float hn = om * n + zh;
    hold = hn;                           // exact fp32 state (replicated lanes)
    if (g16 == 0) {                      // one writer replica per wave
      encb[t * H_ + u] = hn;
      h16[cur ^ 1][u] = f2h(hn);
    }
    __syncthreads();                     // new h visible to all waves
  }
}

// ---------- heads: 512 blocks, fused lower-chol fill + in-block anchor ---------
// Each block owns 32 (b,t) rows. Matvec outputs: mean_z/mean_x/cov_x direct;
// pz diag/off: d<4 staged in LDS then the block writes its rows' FULL lower
// chol rows (zero+diag+off, coalesced float4); d=4..7 scattered directly into
// the upper half (zeroed by gru tail blocks; stream order guarantees done).
// Lower-half writes are safe: d=0..2 rows overlap only dead xp scratch; d=3
// rows overlap exactly this block's own enc rows (already staged in LDS).
// Blocks owning t=0 also compute anchor[b] from the LDS copy.
__global__ __launch_bounds__(384) void heads_kernel(
    const float* __restrict__ enc, const float* __restrict__ WheadT,
    const float* __restrict__ b_mz, const float* __restrict__ b_mx,
    const float* __restrict__ b_pz, const float* __restrict__ b_cx,
    float* __restrict__ out_meanz, float* __restrict__ out_meanx,
    float* __restrict__ out_covx, float* __restrict__ chol,
    float* __restrict__ anchor, const float* __restrict__ W_mx) {
  __shared__ float el[32 * 256];         // 32 KB
  __shared__ float dsd[32][4], dso[32][4];
  __shared__ float redA[4], redB[4];
  int tid = threadIdx.x;
  int row0 = blockIdx.x * 32;
  const float4* e4 = (const float4*)(enc + (size_t)row0 * 256);
  float4* el4 = (float4*)el;
#pragma unroll
  for (int i = 0; i < 6; ++i) {
    int idx = i * 384 + tid;             // 2048 float4 = 32x64
    if (idx < 2048) el4[idx] = e4[idx];
  }
  __syncthreads();
  int rg = tid / 96, c = tid - rg * 96;  // rg in [0,4), c in [0,96)
  const float4* Wc = (const float4*)(WheadT + c * 256);
  float acc[8];
#pragma unroll
  for (int r = 0; r < 8; ++r) acc[r] = 0.f;
  for (int k4 = 0; k4 < 64; ++k4) {
    float4 w4 = Wc[k4];
#pragma unroll
    for (int r = 0; r < 8; ++r) {
      float4 ev = el4[(rg * 8 + r) * 64 + k4];
      acc[r] += w4.x * ev.x; acc[r] += w4.y * ev.y;
      acc[r] += w4.z * ev.z; acc[r] += w4.w * ev.w;
    }
  }
#pragma unroll
  for (int r = 0; r < 8; ++r) {
    int lr = rg * 8 + r;
    int row = row0 + lr;
    float a_ = acc[r];
    if (c < 8) {
      out_meanz[(size_t)row * 8 + c] = a_ + b_mz[c];
    } else if (c < 16) {
      int d = c - 8;
      out_meanx[(size_t)row * 8 + d] = a_ + b_mx[d];   // anchor applied later
    } else if (c < 32) {
      int d = c - 16;
      float v = a_ + b_pz[d];
      if (d < 8)                          // diag: softplus (stable)
        v = (v > 0.f) ? (v + log1pf(__expf(-v))) : log1pf(__expf(v));
      int bb = row >> 8, tt = row & 255;
      if (d < 4) {
        dsd[lr][d] = v;                                 // lower diag (LDS)
      } else if (d < 8) {                               // upper diag: direct
        chol[(((size_t)d * 64 + bb) * 256 + tt) * 256 + tt] = v;
      } else if (d < 12) {
        dso[lr][d - 8] = v;                             // lower off (LDS)
      } else {                                          // upper off: direct
        int dd = d - 8;
        if (tt < 255)
          chol[(((size_t)dd * 64 + bb) * 256 + tt) * 256 + tt + 1] = v;
      }
    } else {
      int d = c - 32;
      out_covx[(size_t)row * 64 + d] = a_ + b_cx[d];
    }
  }
  // in-block anchor for blocks owning t=0 (reads the LDS enc copy, race-free)
  bool anch = (row0 & 255) == 0;
  if (anch && tid < 256) {
    float e0 = el[tid];
    float va0 = e0 * W_mx[tid];
    float va1 = e0 * W_mx[256 + tid];
#pragma unroll
    for (int off = 32; off >= 1; off >>= 1) {
      va0 += __shfl_down(va0, off, 64);
      va1 += __shfl_down(va1, off, 64);
    }
    if ((tid & 63) == 0) { redA[tid >> 6] = va0; redB[tid >> 6] = va1; }
  }
  __syncthreads();                       // dsd/dso/red visible
  if (anch && tid == 0) {
    int b = row0 >> 8;
    anchor[b * 2 + 0] = b_mx[0] + ((redA[0] + redA[1]) + (redA[2] + redA[3]));
    anchor[b * 2 + 1] = b_mx[1] + ((redB[0] + redB[1]) + (redB[2] + redB[3]));
  }
  // cooperative lower-half row fill: 4 d x 32 rows x 64 float4 = 8192
  float4* chol4 = (float4*)chol;
  for (int idx = tid; idx < 8192; idx += 384) {
    int j = idx & 63, lr = (idx >> 6) & 31, d = idx >> 11;
    int grow = row0 + lr;
    int bb = grow >> 8, tt = grow & 255;
    int jd = tt >> 2, jo = (tt + 1) >> 2;            // jo==64 at tt==255: excluded
    float vd = (j == jd) ? dsd[lr][d] : 0.f;
    float vo = (j == jo) ? dso[lr][d] : 0.f;
    int te = tt & 3, oe = (tt + 1) & 3;
    float4 v;
    v.x = (te == 0 ? vd : 0.f) + (oe == 0 ? vo : 0.f);
    v.y = (te == 1 ? vd : 0.f) + (oe == 1 ? vo : 0.f);
    v.z = (te == 2 ? vd : 0.f) + (oe == 2 ? vo : 0.f);
    v.w = (te == 3 ? vd : 0.f) + (oe == 3 ? vo : 0.f);
    chol4[(((size_t)d * 64 + bb) * 256 + tt) * 64 + j] = v;
  }
}

// ---------- final: mean_x anchor fix only (32768 elements) ----------
__global__ __launch_bounds__(256) void chol_fin(
    const float* __restrict__ anchor, float* __restrict__ mean_x) {
  int j = blockIdx.x * 256 + threadIdx.x;   // 128 blocks x 256 = 32768
  int row = j >> 1, d = j & 1;
  mean_x[(size_t)row * 8 + d] -= anchor[(row >> 8) * 2 + d];
}

extern "C" void kernel_launch(void* const* d_in, const int* in_sizes, int n_in,
                              void* d_out, int out_size, void* d_ws, size_t ws_size,
                              hipStream_t stream) {
  const float* y    = (const float*)d_in[0];
  const float* W_ih = (const float*)d_in[1];
  const float* W_hh = (const float*)d_in[2];
  const float* b_ih = (const float*)d_in[3];
  const float* b_hh = (const float*)d_in[4];
  const float* W_mz = (const float*)d_in[5];
  const float* b_mz = (const float*)d_in[6];
  const float* W_mx = (const float*)d_in[7];
  const float* b_mx = (const float*)d_in[8];
  const float* W_pz = (const float*)d_in[9];
  const float* b_pz = (const float*)d_in[10];
  const float* W_cx = (const float*)d_in[11];
  const float* b_cx = (const float*)d_in[12];

  float* out    = (float*)d_out;
  float* mean_z = out;                    // [64,256,8]
  float* chol   = out + 131072;           // [8,64,256,256]
  float* mean_x = out + 33685504;         // [16384,8]
  float* cov_x  = out + 33816576;         // [16384,8,8]

  float* ws      = (float*)d_ws;
  float* WT_ih   = ws;                    // 98304
  float* WheadT  = ws + 98304;            // 24576
  unsigned* Wreg = (unsigned*)(ws + 122880); // 98304
  float* anchor  = ws + 221184;           // 128

  // large scratch inside the chol LOWER half (rewritten by heads at end);
  // upper half [16777216,33554432) is zeroed by gru tail blocks (overlapped).
  float* xp  = chol;                      // 12582912 floats
  float* enc = chol + 12582912;           // 4194304 floats (ends at 16777216)

  prep_kernel<<<864, 256, 0, stream>>>(W_ih, W_hh, W_mz, W_mx, W_pz, W_cx,
                                       WT_ih, WheadT, Wreg);
  xproj_kernel<<<512, 256, 0, stream>>>(y, WT_ih, b_ih, b_hh, xp);
  gru_kernel<<<160, 1024, 0, stream>>>(xp, Wreg, b_hh, enc,
                                       ((float4*)chol) + 4194304);
  heads_kernel<<<512, 384, 0, stream>>>(enc, WheadT, b_mz, b_mx, b_pz, b_cx,
                                        mean_z, mean_x, cov_x, chol,
                                        anchor, W_mx);
  chol_fin<<<128, 256, 0, stream>>>(anchor, mean_x);
}

// Round 12
// 504.254 us; speedup vs baseline: 1.5134x; 1.0648x over previous
//
#include <hip/hip_runtime.h>
#include <cstdint>
#include <cstddef>

#define B_   64
#define T_   256
#define DIN_ 128
#define H_   256
#define G3_  768   // 3*H

typedef _Float16 f16x8 __attribute__((ext_vector_type(8)));
typedef float    f32x4 __attribute__((ext_vector_type(4)));

#define MFMA(a, b, c) __builtin_amdgcn_mfma_f32_16x16x32_f16((a), (b), (c), 0, 0, 0)

// ---------- helpers ----------
__device__ __forceinline__ unsigned short f2h(float f) {
  _Float16 h = (_Float16)f;              // v_cvt_f16_f32 (RNE)
  return __builtin_bit_cast(unsigned short, h);
}

// ---------- prep ----------
// Wreg layout for 16-wave MFMA gru (1024 threads/block):
//   frag index fi = g*8 + kf   (g=gate 0..2, kf=K-frag 0..7)
//   thread tid: wave w=tid>>6, lane l=tid&63; output u = w*16 + (l&15)
//   B-frag dword d holds fp16 pair (k, k+1), k = kf*32 + (l>>4)*8 + 2d
//   Wreg dword m = (fi*1024 + tid)*4 + d -> coalesced uint4 loads W4[fi*1024+tid]
__global__ __launch_bounds__(256) void prep_kernel(
    const float* __restrict__ W_ih, const float* __restrict__ W_hh,
    const float* __restrict__ W_mz, const float* __restrict__ W_mx,
    const float* __restrict__ W_pz, const float* __restrict__ W_cx,
    float* __restrict__ WT_ih, float* __restrict__ WheadT,
    unsigned* __restrict__ Wreg) {
  int i = blockIdx.x * 256 + threadIdx.x;
  if (i < 98304) {                       // WT_ih[k*768+g] = W_ih[g*128+k]
    int k = i / 768, g = i % 768;
    WT_ih[i] = W_ih[g * 128 + k];
  } else if (i < 98304 + 24576) {        // WheadT[c*256+k]
    int j = i - 98304;
    int c = j >> 8, k = j & 255;
    float v;
    if (c < 8)       v = W_mz[c * 256 + k];
    else if (c < 16) v = W_mx[(c - 8) * 256 + k];
    else if (c < 32) v = W_pz[(c - 16) * 256 + k];
    else             v = W_cx[(c - 32) * 256 + k];
    WheadT[j] = v;
  } else {                               // W_hh fp16 B-frag repack (16-wave layout)
    int m = i - 122880;                  // 0..98303
    int d = m & 3, n = m >> 2;           // d = frag dword
    int tid = n & 1023, fi = n >> 10;    // fi in [0,24)
    int g  = fi >> 3, kf = fi & 7;
    int wv = tid >> 6, l = tid & 63;
    int u = wv * 16 + (l & 15);
    int k = kf * 32 + ((l >> 4) << 3) + 2 * d;
    int row = g * 256 + u;
    unsigned short lo = f2h(W_hh[row * 256 + k]);
    unsigned short hi = f2h(W_hh[row * 256 + k + 1]);
    Wreg[m] = ((unsigned)hi << 16) | (unsigned)lo;
  }
}

// ---------- x_proj = y @ W_ih^T + b_ih (+ b_hh folded for r,z gates) ----------
// 512 blocks: blockIdx>>1 selects 64-row stripe, blockIdx&1 selects 3 of 6 col-tiles.
__global__ __launch_bounds__(256) void xproj_kernel(
    const float* __restrict__ y, const float* __restrict__ WT_ih,
    const float* __restrict__ b_ih, const float* __restrict__ b_hh,
    float* __restrict__ xp) {
  __shared__ float ylds[64][132];
  int tid = threadIdx.x;
  int row0 = (blockIdx.x >> 1) * 64;
  int c0 = (blockIdx.x & 1) * 3;
  const float4* y4 = (const float4*)(y + (size_t)row0 * DIN_);
#pragma unroll
  for (int i = 0; i < 8; ++i) {
    int idx = i * 256 + tid;             // 2048 float4 = 64x128
    float4 v = y4[idx];
    int r = idx >> 5, c4 = (idx & 31) * 4;
    ylds[r][c4 + 0] = v.x; ylds[r][c4 + 1] = v.y;
    ylds[r][c4 + 2] = v.z; ylds[r][c4 + 3] = v.w;
  }
  __syncthreads();
  int tx = tid & 15, ty = tid >> 4;      // thread: 4 rows x 8 cols
  for (int c = c0; c < c0 + 3; ++c) {
    int col0 = c * 128 + tx * 8;
    float acc[4][8];
#pragma unroll
    for (int a = 0; a < 4; ++a)
#pragma unroll
      for (int b = 0; b < 8; ++b) acc[a][b] = 0.f;
#pragma unroll 4
    for (int k = 0; k < 128; ++k) {
      float4 w0 = *(const float4*)&WT_ih[k * 768 + col0];
      float4 w1 = *(const float4*)&WT_ih[k * 768 + col0 + 4];
      float a0 = ylds[ty * 4 + 0][k], a1 = ylds[ty * 4 + 1][k];
      float a2 = ylds[ty * 4 + 2][k], a3 = ylds[ty * 4 + 3][k];
      acc[0][0] += a0 * w0.x; acc[0][1] += a0 * w0.y; acc[0][2] += a0 * w0.z; acc[0][3] += a0 * w0.w;
      acc[0][4] += a0 * w1.x; acc[0][5] += a0 * w1.y; acc[0][6] += a0 * w1.z; acc[0][7] += a0 * w1.w;
      acc[1][0] += a1 * w0.x; acc[1][1] += a1 * w0.y; acc[1][2] += a1 * w0.z; acc[1][3] += a1 * w0.w;
      acc[1][4] += a1 * w1.x; acc[1][5] += a1 * w1.y; acc[1][6] += a1 * w1.z; acc[1][7] += a1 * w1.w;
      acc[2][0] += a2 * w0.x; acc[2][1] += a2 * w0.y; acc[2][2] += a2 * w0.z; acc[2][3] += a2 * w0.w;
      acc[2][4] += a2 * w1.x; acc[2][5] += a2 * w1.y; acc[2][6] += a2 * w1.z; acc[2][7] += a2 * w1.w;
      acc[3][0] += a3 * w0.x; acc[3][1] += a3 * w0.y; acc[3][2] += a3 * w0.z; acc[3][3] += a3 * w0.w;
      acc[3][4] += a3 * w1.x; acc[3][5] += a3 * w1.y; acc[3][6] += a3 * w1.z; acc[3][7] += a3 * w1.w;
    }
    float4 b0 = *(const float4*)&b_ih[col0];
    float4 b1 = *(const float4*)&b_ih[col0 + 4];
    if (c < 4) {                         // fold b_hh into r,z gate columns (<512)
      float4 h0 = *(const float4*)&b_hh[col0];
      float4 h1 = *(const float4*)&b_hh[col0 + 4];
      b0.x += h0.x; b0.y += h0.y; b0.z += h0.z; b0.w += h0.w;
      b1.x += h1.x; b1.y += h1.y; b1.z += h1.z; b1.w += h1.w;
    }
#pragma unroll
    for (int a = 0; a < 4; ++a) {
      int row = row0 + ty * 4 + a;
      float4 o0, o1;
      o0.x = acc[a][0] + b0.x; o0.y = acc[a][1] + b0.y; o0.z = acc[a][2] + b0.z; o0.w = acc[a][3] + b0.w;
      o1.x = acc[a][4] + b1.x; o1.y = acc[a][5] + b1.y; o1.z = acc[a][6] + b1.z; o1.w = acc[a][7] + b1.w;
      *(float4*)&xp[(size_t)row * G3_ + col0] = o0;
      *(float4*)&xp[(size_t)row * G3_ + col0 + 4] = o1;
    }
  }
}

// ---------- GRU recurrence via MFMA: blocks 0-63; blocks 64-159 zero chol upper --
// 16 waves x 64 lanes. Wave w owns outputs [16w, 16w+16) for all 3 gates.
// Round-7-verified inner loop (per-kf: ONE h-frag, R/Z/N interleaved, minimal
// live VGPR state). This round: t-loop unrolled x2 with COMPILE-TIME cur and
// running xp/enc pointers — removes per-step index VALU that competes with
// MFMA on the shared SIMD issue port. MFMA order unchanged.
__global__ __launch_bounds__(1024) void gru_kernel(
    const float* __restrict__ xp, const unsigned* __restrict__ Wreg,
    const float* __restrict__ b_hh, float* enc, float4* __restrict__ cholU) {
  int tid = threadIdx.x;
  int b = blockIdx.x;
  if (b >= 64) {                         // ---- tail blocks: zero chol upper half
    float4 zz = {0.f, 0.f, 0.f, 0.f};    //      (concurrent with the recurrence)
    int idx = (b - 64) * 1024 + tid;     // 96*1024 = 98304 threads
    for (; idx < 4194304; idx += 98304) cholU[idx] = zz;
    return;
  }
  int w = tid >> 6;
  int l = tid & 63;
  int g16 = l >> 4;                      // replica / K-chunk group
  int u = w * 16 + (l & 15);
  __shared__ alignas(16) unsigned short h16[2][256];   // double-buffered h

  f16x8 wfR[8], wfZ[8], wfN[8];          // W_hh B-frags (AGPR-resident, ok)
  const uint4* W4 = (const uint4*)Wreg;
#pragma unroll
  for (int kf = 0; kf < 8; ++kf) {
    wfR[kf] = __builtin_bit_cast(f16x8, W4[(0 * 8 + kf) * 1024 + tid]);
    wfZ[kf] = __builtin_bit_cast(f16x8, W4[(1 * 8 + kf) * 1024 + tid]);
    wfN[kf] = __builtin_bit_cast(f16x8, W4[(2 * 8 + kf) * 1024 + tid]);
  }
  if (tid < 32) {                        // h0 = 0 (buffer 0 = first 32 uint4)
    uint4 z = {0u, 0u, 0u, 0u};
    ((uint4*)h16)[tid] = z;
  }
  const float* xq = xp + (size_t)b * (T_ * G3_);
  float* ep = enc + (size_t)b * (T_ * H_);
  float bhn = b_hh[512 + u];
  float hold = 0.f;
  const f32x4 z4 = {0.f, 0.f, 0.f, 0.f};
  __syncthreads();
  const uint4* h4 = (const uint4*)h16;

#define GSTEP(CUR)                                                             \
  {                                                                            \
    asm volatile("" ::: "memory");       /* keep load placement per-step */    \
    float xr = xq[u], xz = xq[256 + u], xn = xq[512 + u];                      \
    f32x4 aR, aZ, aN;                                                          \
    {                                                                          \
      uint4 hq = h4[(CUR) * 32 + g16];                                         \
      f16x8 hk = __builtin_bit_cast(f16x8, hq);                                \
      aR = MFMA(hk, wfR[0], z4);                                               \
      aZ = MFMA(hk, wfZ[0], z4);                                               \
      aN = MFMA(hk, wfN[0], z4);                                               \
    }                                                                          \
    _Pragma("unroll")                                                          \
    for (int kf = 1; kf < 8; ++kf) {                                           \
      uint4 hq = h4[(CUR) * 32 + kf * 4 + g16];                                \
      f16x8 hk = __builtin_bit_cast(f16x8, hq);                                \
      aR = MFMA(hk, wfR[kf], aR);                                              \
      aZ = MFMA(hk, wfZ[kf], aZ);                                              \
      aN = MFMA(hk, wfN[kf], aN);                                              \
    }                                                                          \
    float pr = aR[0] + xr, pz = aZ[0] + xz;                                    \
    float r_ = 1.f / (1.f + __expf(-pr));                                      \
    float q_ = 1.f / (1.f + __expf(-pz));                                      \
    float zh = q_ * hold, om = 1.f - q_;                                       \
    float pn = aN[0] + bhn;                                                    \
    float a = xn + r_ * pn;                                                    \
    a = fminf(15.f, fmaxf(-15.f, a));                                          \
    float e = __expf(2.f * a);                                                 \
    float n = (e - 1.f) / (e + 1.f);     /* tanh */                            \
    float hn = om * n + zh;                                                    \
    hold = hn;                           /* exact fp32 state (replicas) */     \
    if (g16 == 0) {                      /* one writer replica per wave */     \
      ep[u] = hn;                                                              \
      h16[(CUR) ^ 1][u] = f2h(hn);                                             \
    }                                                                          \
    ep += H_; xq += G3_;                                                       \
    __syncthreads();                     /* new h visible to all waves */      \
  }

  for (int t = 0; t < T_; t += 2) {
    GSTEP(0)
    GSTEP(1)
  }
#undef GSTEP
}

// ---------- heads: 512 blocks, fused lower-chol fill + inline anchor ----------
// Each block owns 32 (b,t) rows (all same batch b). Matvec outputs:
// mean_z/cov_x direct; mean_x d<2 gets the anchor subtraction INLINE —
// every block computes dot(enc[b,0,:], W_mx[d,:]) itself (global enc is
// L2-hot; b_mx cancels algebraically: out = acc - dot). pz diag/off: d<4
// staged in LDS then the block writes its rows' FULL lower chol rows
// (zero+diag+off, coalesced float4); d=4..7 scattered directly into the
// upper half (zeroed by gru tail blocks; stream order guarantees done).
// Lower-half writes are safe: d=0..2 rows overlap only dead xp scratch; d=3
// rows overlap exactly this block's own enc rows (already staged in LDS).
__global__ __launch_bounds__(384) void heads_kernel(
    const float* __restrict__ enc, const float* __restrict__ WheadT,
    const float* __restrict__ b_mz, const float* __restrict__ b_mx,
    const float* __restrict__ b_pz, const float* __restrict__ b_cx,
    float* __restrict__ out_meanz, float* __restrict__ out_meanx,
    float* __restrict__ out_covx, float* __restrict__ chol,
    const float* __restrict__ W_mx) {
  __shared__ float el[32 * 256];         // 32 KB
  __shared__ float dsd[32][4], dso[32][4];
  __shared__ float red[8];
  int tid = threadIdx.x;
  int row0 = blockIdx.x * 32;
  int bb0 = row0 >> 8;                   // this block's batch index
  const float4* e4 = (const float4*)(enc + (size_t)row0 * 256);
  float4* el4 = (float4*)el;
#pragma unroll
  for (int i = 0; i < 6; ++i) {
    int idx = i * 384 + tid;             // 2048 float4 = 32x64
    if (idx < 2048) el4[idx] = e4[idx];
  }
  __syncthreads();
  int rg = tid / 96, c = tid - rg * 96;  // rg in [0,4), c in [0,96)
  const float4* Wc = (const float4*)(WheadT + c * 256);
  float acc[8];
#pragma unroll
  for (int r = 0; r < 8; ++r) acc[r] = 0.f;
  for (int k4 = 0; k4 < 64; ++k4) {
    float4 w4 = Wc[k4];
#pragma unroll
    for (int r = 0; r < 8; ++r) {
      float4 ev = el4[(rg * 8 + r) * 64 + k4];
      acc[r] += w4.x * ev.x; acc[r] += w4.y * ev.y;
      acc[r] += w4.z * ev.z; acc[r] += w4.w * ev.w;
    }
  }
  // anchor dot for this block's batch: dot(enc[b,0,:], W_mx[d,:]), d=0,1
  if (tid < 256) {
    float e0 = enc[(size_t)bb0 * (T_ * H_) + tid];    // L2-hot
    float va0 = e0 * W_mx[tid];
    float va1 = e0 * W_mx[256 + tid];
#pragma unroll
    for (int off = 32; off >= 1; off >>= 1) {
      va0 += __shfl_down(va0, off, 64);
      va1 += __shfl_down(va1, off, 64);
    }
    if ((tid & 63) == 0) { red[tid >> 6] = va0; red[4 + (tid >> 6)] = va1; }
  }
  __syncthreads();                       // red visible
  float anc0 = (red[0] + red[1]) + (red[2] + red[3]);
  float anc1 = (red[4] + red[5]) + (red[6] + red[7]);
#pragma unroll
  for (int r = 0; r < 8; ++r) {
    int lr = rg * 8 + r;
    int row = row0 + lr;
    float a_ = acc[r];
    if (c < 8) {
      out_meanz[(size_t)row * 8 + c] = a_ + b_mz[c];
    } else if (c < 16) {
      int d = c - 8;
      float o = a_ + b_mx[d];
      if (d == 0) o = a_ - anc0;         // b_mx[0] cancels in anchor subtraction
      if (d == 1) o = a_ - anc1;
      out_meanx[(size_t)row * 8 + d] = o;
    } else if (c < 32) {
      int d = c - 16;
      float v = a_ + b_pz[d];
      if (d < 8)                          // diag: softplus (stable)
        v = (v > 0.f) ? (v + log1pf(__expf(-v))) : log1pf(__expf(v));
      int bb = row >> 8, tt = row & 255;
      if (d < 4) {
        dsd[lr][d] = v;                                 // lower diag (LDS)
      } else if (d < 8) {                               // upper diag: direct
        chol[(((size_t)d * 64 + bb) * 256 + tt) * 256 + tt] = v;
      } else if (d < 12) {
        dso[lr][d - 8] = v;                             // lower off (LDS)
      } else {                                          // upper off: direct
        int dd = d - 8;
        if (tt < 255)
          chol[(((size_t)dd * 64 + bb) * 256 + tt) * 256 + tt + 1] = v;
      }
    } else {
      int d = c - 32;
      out_covx[(size_t)row * 64 + d] = a_ + b_cx[d];
    }
  }
  __syncthreads();                       // dsd/dso visible
  // cooperative lower-half row fill: 4 d x 32 rows x 64 float4 = 8192
  float4* chol4 = (float4*)chol;
  for (int idx = tid; idx < 8192; idx += 384) {
    int j = idx & 63, lr = (idx >> 6) & 31, d = idx >> 11;
    int grow = row0 + lr;
    int bb = grow >> 8, tt = grow & 255;
    int jd = tt >> 2, jo = (tt + 1) >> 2;            // jo==64 at tt==255: excluded
    float vd = (j == jd) ? dsd[lr][d] : 0.f;
    float vo = (j == jo) ? dso[lr][d] : 0.f;
    int te = tt & 3, oe = (tt + 1) & 3;
    float4 v;
    v.x = (te == 0 ? vd : 0.f) + (oe == 0 ? vo : 0.f);
    v.y = (te == 1 ? vd : 0.f) + (oe == 1 ? vo : 0.f);
    v.z = (te == 2 ? vd : 0.f) + (oe == 2 ? vo : 0.f);
    v.w = (te == 3 ? vd : 0.f) + (oe == 3 ? vo : 0.f);
    chol4[(((size_t)d * 64 + bb) * 256 + tt) * 64 + j] = v;
  }
}

extern "C" void kernel_launch(void* const* d_in, const int* in_sizes, int n_in,
                              void* d_out, int out_size, void* d_ws, size_t ws_size,
                              hipStream_t stream) {
  const float* y    = (const float*)d_in[0];
  const float* W_ih = (const float*)d_in[1];
  const float* W_hh = (const float*)d_in[2];
  const float* b_ih = (const float*)d_in[3];
  const float* b_hh = (const float*)d_in[4];
  const float* W_mz = (const float*)d_in[5];
  const float* b_mz = (const float*)d_in[6];
  const float* W_mx = (const float*)d_in[7];
  const float* b_mx = (const float*)d_in[8];
  const float* W_pz = (const float*)d_in[9];
  const float* b_pz = (const float*)d_in[10];
  const float* W_cx = (const float*)d_in[11];
  const float* b_cx = (const float*)d_in[12];

  float* out    = (float*)d_out;
  float* mean_z = out;                    // [64,256,8]
  float* chol   = out + 131072;           // [8,64,256,256]
  float* mean_x = out + 33685504;         // [16384,8]
  float* cov_x  = out + 33816576;         // [16384,8,8]

  float* ws      = (float*)d_ws;
  float* WT_ih   = ws;                    // 98304
  float* WheadT  = ws + 98304;            // 24576
  unsigned* Wreg = (unsigned*)(ws + 122880); // 98304

  // large scratch inside the chol LOWER half (rewritten by heads at end);
  // upper half [16777216,33554432) is zeroed by gru tail blocks (overlapped).
  float* xp  = chol;                      // 12582912 floats
  float* enc = chol + 12582912;           // 4194304 floats (ends at 16777216)

  prep_kernel<<<864, 256, 0, stream>>>(W_ih, W_hh, W_mz, W_mx, W_pz, W_cx,
                                       WT_ih, WheadT, Wreg);
  xproj_kernel<<<512, 256, 0, stream>>>(y, WT_ih, b_ih, b_hh, xp);
  gru_kernel<<<160, 1024, 0, stream>>>(xp, Wreg, b_hh, enc,
                                       ((float4*)chol) + 4194304);
  heads_kernel<<<512, 384, 0, stream>>>(enc, WheadT, b_mz, b_mx, b_pz, b_cx,
                                        mean_z, mean_x, cov_x, chol, W_mx);
}